// Round 13
// baseline (236.180 us; speedup 1.0000x reference)
//
#include <hip/hip_runtime.h>
#include <hip/hip_bf16.h>

#define HH 96
#define WW 96
#define NPIX 9216
#define NCH 128
#define DDIM 1152
#define TOTAL_ELEMS 1179648
#define CG 32
#define DDIAG 9217
#define DROW 884832

// dist tile params: 8 n x 512 m, 3 bands of 10x528 staged in LDS (31.7KB)
#define NTIL 8
#define MTIL 512
#define BROWS 10
#define BCOLS 528
#define BELEMS (BROWS * BCOLS)          // 5280
#define DCHUNKS 1980                    // 3*BELEMS/8
#define NTB 1152
#define DBLK 20736                      // NTB*18

typedef float f32x4 __attribute__((ext_vector_type(4)));
typedef __bf16 bf16x8 __attribute__((ext_vector_type(8)));
typedef _Float16 half8 __attribute__((ext_vector_type(8)));

__device__ __forceinline__ void gload_lds16(const void* g, void* l) {
  __builtin_amdgcn_global_load_lds((const __attribute__((address_space(1))) void*)g,
                                   (__attribute__((address_space(3))) void*)l, 16, 0, 0);
}

// ======================= NEW PATH (G-factorized, f16) =======================
#define GUARD_ELEMS 894064ull
constexpr size_t G_CORE_ELEMS = (size_t)NPIX * NPIX;
constexpr size_t G_TOT_ELEMS = G_CORE_ELEMS + 2ull * GUARD_ELEMS;
constexpr size_t GBYTES = ((G_TOT_ELEMS * 2 + 255) & ~(size_t)255);
constexpr size_t CT_OFF = GBYTES;
constexpr size_t ST2_OFF = CT_OFF + (size_t)NPIX * NCH * 2;
constexpr size_t STYT_OFF = ST2_OFF + (size_t)NPIX * NCH * 2;
constexpr size_t SS_OFF = STYT_OFF + (size_t)NPIX * NCH * 4;
constexpr size_t RN2_OFF = SS_OFF + (size_t)NPIX * 4;
constexpr size_t KEY2_OFF = RN2_OFF + (size_t)NPIX * 4;
constexpr size_t NEED_NEW = KEY2_OFF + (size_t)NPIX * 8;
constexpr long GUARD_I4 = 111758;        // GUARD_ELEMS*2/16

// features [c][pix] f32 -> [pix][c] f16 (+ styT f32, per-pixel ss); also zeroes keytab/out
__global__ __launch_bounds__(256)
void transpose_kernel(const float* __restrict__ style_f, const float* __restrict__ content_f,
                      _Float16* __restrict__ St, _Float16* __restrict__ Ct,
                      float* __restrict__ styT, float* __restrict__ ss,
                      unsigned long long* __restrict__ keytab, float* __restrict__ out) {
  __shared__ float ftile[NCH][97];
  const int y = blockIdx.x;
  const bool is_style = (blockIdx.y == 0);
  const float* f = is_style ? style_f : content_f;
  _Float16* P = is_style ? St : Ct;
  const int tid = threadIdx.x;
  if (is_style) {
    int g = y * 256 + tid;
    if (g < NPIX) keytab[g] = 0ull;
    if (g == 0) *out = 0.f;
  }
  for (int i = tid; i < NCH * WW; i += 256) {
    int c = i / WW, x = i - (i / WW) * WW;
    ftile[c][x] = f[(size_t)c * NPIX + y * WW + x];
  }
  __syncthreads();
  for (int j = tid; j < WW * NCH; j += 256) {
    int x = j >> 7, c = j & 127;
    float v = ftile[c][x];
    P[(size_t)(y * WW + x) * NCH + c] = (_Float16)v;
    if (is_style) styT[(size_t)(y * WW + x) * NCH + c] = v;
  }
  if (is_style && tid < WW) {
    float s = 0.f;
#pragma unroll 8
    for (int c = 0; c < NCH; ++c) { float v = ftile[c][tid]; s = fmaf(v, v, s); }
    ss[y * WW + tid] = s;
  }
}

__global__ __launch_bounds__(256)
void boxnorm_kernel(const float* __restrict__ ss, float* __restrict__ rnorm) {
  int m = blockIdx.x * 256 + threadIdx.x;
  int ym = m / WW, xm = m - (m / WW) * WW;
  float s = 0.f;
#pragma unroll
  for (int di = -1; di <= 1; ++di) {
    int yy = ym + di;
    if (yy < 0 || yy >= HH) continue;
#pragma unroll
    for (int dj = -1; dj <= 1; ++dj) {
      int xx = xm + dj;
      if (xx < 0 || xx >= WW) continue;
      s += ss[yy * WW + xx];
    }
  }
  rnorm[m] = 1.0f / fmaxf(sqrtf(s), 1e-12f);
}

// G-GEMM (also zeroes the guard bands: 22 int4/side/block, disjoint from core)
__global__ __launch_bounds__(256, 2)
void ggemm_kernel(const _Float16* __restrict__ Ct, const _Float16* __restrict__ St,
                  unsigned short* __restrict__ Gg) {
  __shared__ char smem[65536];
  const int tid = threadIdx.x;
  const int lane = tid & 63, wid = tid >> 6;
  const int l15 = lane & 15, lg = lane >> 4;
  const int wm = wid >> 1, wn = wid & 1;
  const int n0 = blockIdx.x * 128, m0 = blockIdx.y * 128;

  {  // guard zeroing
    const long bidf = (long)blockIdx.y * gridDim.x + blockIdx.x;
    if (tid < 64) {
      int side = tid >> 5, k = tid & 31;
      if (k < 22) {
        long q = bidf * 22 + k;
        if (q < GUARD_I4) {
          int4 z = {0, 0, 0, 0};
          _Float16* gp = (_Float16*)Gg + (side ? (long)(GUARD_ELEMS + G_CORE_ELEMS) : 0l);
          *(int4*)(gp + q * 8) = z;
        }
      }
    }
  }
  {  // stage A,B with slot-XOR swizzle
    const int r = tid >> 4, p = tid & 15;
    const int l = p ^ (r & 7);
    const _Float16* sa = Ct + (size_t)(n0 + r) * NCH + l * 8;
    const _Float16* sb = St + (size_t)(m0 + r) * NCH + l * 8;
    char* d = smem + tid * 16;
#pragma unroll
    for (int i = 0; i < 8; ++i) {
      gload_lds16(sa + (size_t)16 * i * NCH, d + 4096 * i);
      gload_lds16(sb + (size_t)16 * i * NCH, d + 32768 + 4096 * i);
    }
  }
  __syncthreads();

  f32x4 acc[4][4];
#pragma unroll
  for (int mf = 0; mf < 4; ++mf)
#pragma unroll
    for (int nf = 0; nf < 4; ++nf) {
      f32x4 z = {0.f, 0.f, 0.f, 0.f};
      acc[mf][nf] = z;
    }
#pragma unroll
  for (int ks = 0; ks < 4; ++ks) {
    half8 af[4], bb[4];
#pragma unroll
    for (int mf = 0; mf < 4; ++mf) {
      int row = wm * 64 + mf * 16 + l15;
      int phys = (ks * 4 + lg) ^ (row & 7);
      af[mf] = __builtin_bit_cast(half8, *(const int4*)(smem + row * 256 + phys * 16));
    }
#pragma unroll
    for (int nf = 0; nf < 4; ++nf) {
      int row = wn * 64 + nf * 16 + l15;
      int phys = (ks * 4 + lg) ^ (row & 7);
      bb[nf] = __builtin_bit_cast(half8, *(const int4*)(smem + 32768 + row * 256 + phys * 16));
    }
#pragma unroll
    for (int mf = 0; mf < 4; ++mf)
#pragma unroll
      for (int nf = 0; nf < 4; ++nf)
        acc[mf][nf] = __builtin_amdgcn_mfma_f32_16x16x32_f16(af[mf], bb[nf], acc[mf][nf], 0, 0, 0);
  }
  __syncthreads();
#pragma unroll
  for (int mf = 0; mf < 4; ++mf)
#pragma unroll
    for (int nf = 0; nf < 4; ++nf)
#pragma unroll
      for (int r = 0; r < 4; ++r) {
        int row = wm * 64 + mf * 16 + lg * 4 + r;
        int col = wn * 64 + nf * 16 + l15;
        *(_Float16*)(smem + (row * 136 + col) * 2) = (_Float16)acc[mf][nf][r];
      }
  __syncthreads();
  const size_t gbase = GUARD_ELEMS + (size_t)n0 * NPIX + m0;
#pragma unroll
  for (int j = 0; j < 8; ++j) {
    int idx = j * 256 + tid;
    int row = idx >> 4, ch = idx & 15;
    int4 v = *(const int4*)(smem + (row * 136 + ch * 8) * 2);
    *(int4*)(Gg + gbase + (size_t)row * NPIX + ch * 8) = v;
  }
}

// dist + argmax v6: register row-sharing (4 rows/band/wave, 12 b128) +
// shuffle-sourced edge scalars (lane0/63 masked LDS fixups). Same tap math.
__global__ __launch_bounds__(256, 5)
void dist_argmax_kernel(const _Float16* __restrict__ Gg, const float* __restrict__ rnorm,
                        unsigned long long* __restrict__ keytab) {
  __shared__ _Float16 lds[3 * BELEMS];
  const int bid = blockIdx.x;
  const int idx = (bid & 7) * (DBLK / 8) + (bid >> 3);
  const int mtb = idx / NTB;
  const int ntb = idx - mtb * NTB;
  const int n0 = ntb * NTIL;
  const int m0 = mtb * MTIL;
  const int tid = threadIdx.x;
  const int w = tid >> 6, lane = tid & 63;

  long flat0[3];
#pragma unroll
  for (int b = 0; b < 3; ++b) {
    int di = b - 1;
    flat0[b] = (long)(n0 + 96 * di - 1) * NPIX + (long)(m0 + 96 * di - 8) + (long)GUARD_ELEMS;
  }
#pragma unroll
  for (int k = 0; k < 8; ++k) {
    int q = k * 256 + tid;
    if (q < DCHUNKS) {
      int b = q / 660;
      int rem = q - b * 660;
      int row = rem / 66;
      int c16 = rem - row * 66;
      gload_lds16(Gg + flat0[b] + (long)row * NPIX + c16 * 8, lds + (size_t)q * 8);
    }
  }
  const int mlane = m0 + lane * 8;
  const int ym = mlane / WW;
  const int x8 = mlane - ym * WW;
  const float me0 = (x8 == 0) ? 0.f : 1.f;
  const float me7 = (x8 == 88) ? 0.f : 1.f;
  const bool myr0 = (ym >= 1), myr2 = (ym <= 94);
  float rnv[8];
  *(f32x4*)(rnv) = *(const f32x4*)(rnorm + mlane);
  *(f32x4*)(rnv + 4) = *(const f32x4*)(rnorm + mlane + 4);
  const int col8 = lane * 8 + 8;

  const int r0 = w * 2;
  const int nA = n0 + r0, nB = nA + 1;
  const int ynA = nA / WW, xnA = nA - ynA * WW;
  const int ynB = nB / WW, xnB = nB - ynB * WW;
  const float cn0A = (xnA >= 1) ? 1.f : 0.f, cn2A = (xnA <= 94) ? 1.f : 0.f;
  const float cn0B = (xnB >= 1) ? 1.f : 0.f, cn2B = (xnB <= 94) ? 1.f : 0.f;
  const float bwA[3] = {(myr0 && (ynA >= 1)) ? 1.f : 0.f, 1.f, (myr2 && (ynA <= 94)) ? 1.f : 0.f};
  const float bwB[3] = {(myr0 && (ynB >= 1)) ? 1.f : 0.f, 1.f, (myr2 && (ynB <= 94)) ? 1.f : 0.f};

  asm volatile("s_waitcnt vmcnt(0)" ::: "memory");
  __builtin_amdgcn_s_barrier();

  float dA[8] = {0.f, 0.f, 0.f, 0.f, 0.f, 0.f, 0.f, 0.f};
  float dB[8] = {0.f, 0.f, 0.f, 0.f, 0.f, 0.f, 0.f, 0.f};
#pragma unroll
  for (int b = 0; b < 3; ++b) {
    const _Float16* bp = lds + b * BELEMS + r0 * BCOLS;
    half8 R0 = *(const half8*)(bp + col8);                 // band row r0
    half8 R1 = *(const half8*)(bp + BCOLS + col8);         // r0+1
    half8 R2 = *(const half8*)(bp + 2 * BCOLS + col8);     // r0+2
    half8 R3 = *(const half8*)(bp + 3 * BCOLS + col8);     // r0+3
    float pA = __shfl_up((float)R0[7], 1, 64);
    float pB = __shfl_up((float)R1[7], 1, 64);
    float xA = __shfl_down((float)R2[0], 1, 64);
    float xB = __shfl_down((float)R3[0], 1, 64);
    if (lane == 0) {
      pA = (float)bp[7];
      pB = (float)bp[BCOLS + 7];
    }
    if (lane == 63) {
      xA = (float)bp[2 * BCOLS + 520];
      xB = (float)bp[3 * BCOLS + 520];
    }
    {  // output A: V0=R0, V1=R1, V2=R2
      const float wc = bwA[b];
      const float wl = wc * cn0A, wr = wc * cn2A;
#pragma unroll
      for (int j = 0; j < 8; ++j) dA[j] = fmaf((float)R1[j], wc, dA[j]);
      dA[0] = fmaf(pA, wl * me0, dA[0]);
#pragma unroll
      for (int j = 1; j < 8; ++j) dA[j] = fmaf((float)R0[j - 1], wl, dA[j]);
#pragma unroll
      for (int j = 0; j < 7; ++j) dA[j] = fmaf((float)R2[j + 1], wr, dA[j]);
      dA[7] = fmaf(xA, wr * me7, dA[7]);
    }
    {  // output B: V0=R1, V1=R2, V2=R3
      const float wc = bwB[b];
      const float wl = wc * cn0B, wr = wc * cn2B;
#pragma unroll
      for (int j = 0; j < 8; ++j) dB[j] = fmaf((float)R2[j], wc, dB[j]);
      dB[0] = fmaf(pB, wl * me0, dB[0]);
#pragma unroll
      for (int j = 1; j < 8; ++j) dB[j] = fmaf((float)R1[j - 1], wl, dB[j]);
#pragma unroll
      for (int j = 0; j < 7; ++j) dB[j] = fmaf((float)R3[j + 1], wr, dB[j]);
      dB[7] = fmaf(xB, wr * me7, dB[7]);
    }
  }
  {
    float bv = dA[0] * rnv[0];
    int bj = mlane;
#pragma unroll
    for (int j = 1; j < 8; ++j) {
      float xs = dA[j] * rnv[j];
      if (xs > bv) { bv = xs; bj = mlane + j; }
    }
    float wmx = bv;
#pragma unroll
    for (int mm = 1; mm < 64; mm <<= 1) wmx = fmaxf(wmx, __shfl_xor(wmx, mm, 64));
    if (bv == wmx) {
      unsigned u = __float_as_uint(bv);
      u ^= (unsigned)((int)u >> 31) | 0x80000000u;
      atomicMax(keytab + nA,
                ((unsigned long long)u << 32) | (unsigned)(0xFFFFFFFFu ^ (unsigned)bj));
    }
  }
  {
    float bv = dB[0] * rnv[0];
    int bj = mlane;
#pragma unroll
    for (int j = 1; j < 8; ++j) {
      float xs = dB[j] * rnv[j];
      if (xs > bv) { bv = xs; bj = mlane + j; }
    }
    float wmx = bv;
#pragma unroll
    for (int mm = 1; mm < 64; mm <<= 1) wmx = fmaxf(wmx, __shfl_xor(wmx, mm, 64));
    if (bv == wmx) {
      unsigned u = __float_as_uint(bv);
      u ^= (unsigned)((int)u >> 31) | 0x80000000u;
      atomicMax(keytab + nB,
                ((unsigned long long)u << 32) | (unsigned)(0xFFFFFFFFu ^ (unsigned)bj));
    }
  }
}

// recon+MSE
__global__ __launch_bounds__(256)
void recon_mse2_kernel(const _Float16* __restrict__ Ct, const float* __restrict__ styT,
                       const unsigned long long* __restrict__ keytab, float* __restrict__ out) {
  const int pix = blockIdx.x * 2 + (threadIdx.x >> 7);
  const int c = threadIdx.x & 127;
  const int y = pix / WW, x = pix - (pix / WW) * WW;
  float sum = 0.f, cnt = 0.f;
#pragma unroll
  for (int ki = 0; ki < 3; ++ki) {
    int yn = y - ki + 1;
    if (yn < 0 || yn >= HH) continue;
#pragma unroll
    for (int kj = 0; kj < 3; ++kj) {
      int xn = x - kj + 1;
      if (xn < 0 || xn >= WW) continue;
      cnt += 1.f;
      int m = (int)(0xFFFFFFFFu ^ (unsigned)(keytab[yn * WW + xn] & 0xFFFFFFFFull));
      int ys = m / WW, xs = m - (m / WW) * WW;
      int sy = ys + ki - 1, sx = xs + kj - 1;
      if (sy >= 0 && sy < HH && sx >= 0 && sx < WW)
        sum += styT[(size_t)(sy * WW + sx) * NCH + c];
    }
  }
  float recon = sum / (cnt + 1e-8f);
  float cv = (float)Ct[(size_t)pix * NCH + c];
  float diff = cv - recon;
  float sq = diff * diff;
#pragma unroll
  for (int m = 32; m > 0; m >>= 1) sq += __shfl_down(sq, m, 64);
  __shared__ float wsum[4];
  int lane = threadIdx.x & 63, w = threadIdx.x >> 6;
  if (lane == 0) wsum[w] = sq;
  __syncthreads();
  if (threadIdx.x == 0)
    atomicAdd(out, (wsum[0] + wsum[1] + wsum[2] + wsum[3]) * (1.0f / (float)TOTAL_ELEMS));
}

// ======================= OLD PATH (round-3, fallback) =======================
__global__ __launch_bounds__(256)
void build_patches_old(const float* __restrict__ style_f, const float* __restrict__ content_f,
                       __bf16* __restrict__ Ps, __bf16* __restrict__ Pc) {
  __shared__ float ftile[CG][3][104];
  const int y = blockIdx.x;
  const int cg = blockIdx.y;
  const bool is_style = (blockIdx.z == 0);
  const float* f = is_style ? style_f : content_f;
  __bf16* P = is_style ? Ps : Pc;
  const int tid = threadIdx.x;
  for (int i = tid; i < CG * 3 * 96; i += 256) {
    int cl = i / 288, rem = i - cl * 288;
    int yy = rem / 96, xx = rem - yy * 96;
    int gy = y + yy - 1;
    float v = (gy >= 0 && gy < HH) ? f[(size_t)(cg * CG + cl) * NPIX + gy * WW + xx] : 0.f;
    ftile[cl][yy][xx] = v;
  }
  __syncthreads();
  for (int j = tid; j < 96 * 36; j += 256) {
    int px = j / 36, wi = j - px * 36;
    bf16x8 tmp;
#pragma unroll
    for (int u = 0; u < 8; ++u) {
      int e = wi * 8 + u;
      int cl = e / 9, t = e - cl * 9;
      int ki = t / 3, kj = t - ki * 3;
      int xx = px + kj - 1;
      float v = (xx >= 0 && xx < WW) ? ftile[cl][ki][xx] : 0.f;
      tmp[u] = (__bf16)v;
    }
    *(bf16x8*)(P + (size_t)(y * WW + px) * DDIM + cg * 288 + wi * 8) = tmp;
  }
}

__global__ __launch_bounds__(256)
void norm_old(const __bf16* __restrict__ Ps, float* __restrict__ rnorm) {
  const int n = blockIdx.x * 4 + (threadIdx.x >> 6);
  const int lane = threadIdx.x & 63;
  const bf16x8* row = (const bf16x8*)(Ps + (size_t)n * DDIM);
  float ss = 0.f;
#pragma unroll
  for (int i = 0; i < 3; ++i) {
    int idx = i * 64 + lane;
    if (idx < 144) {
      bf16x8 v = row[idx];
#pragma unroll
      for (int u = 0; u < 8; ++u) { float x = (float)v[u]; ss += x * x; }
    }
  }
#pragma unroll
  for (int m = 1; m < 64; m <<= 1) ss += __shfl_xor(ss, m, 64);
  if (lane == 0) rnorm[n] = 1.0f / fmaxf(sqrtf(ss), 1e-12f);
}

__global__ __launch_bounds__(256, 2)
void gemm_old(const __bf16* __restrict__ Pc, const __bf16* __restrict__ Ps,
              const float* __restrict__ rnorm, unsigned long long* __restrict__ keytab) {
  __shared__ int4 smem4[4608];
  char* smem = (char*)smem4;
  const int tid = threadIdx.x;
  const int lane = tid & 63;
  const int wid = tid >> 6;
  const int l15 = lane & 15;
  const int lg = lane >> 4;
  const int wm = wid >> 1;
  const int wn = wid & 1;
  const int orig = blockIdx.x;
  const int swz = (orig & 7) * 324 + (orig >> 3);
  const int mt = swz / 72;
  const int nt = swz - mt * 72;
  const int bm0 = mt * 256;
  const int sbase = nt * 128;
  const int srow = tid >> 2;
  const int sg = (tid & 3) ^ ((srow >> 1) & 3);
  const __bf16* pa = Pc + (size_t)(bm0 + srow) * DDIM + sg * 8;
  const __bf16* pb = Ps + (size_t)(sbase + srow) * DDIM + sg * 8;
  const int sdst = tid * 16;
  auto stage = [&](int buf, int kt) {
    char* la = smem + buf * 24576 + sdst;
    const int ko = kt * 32;
#pragma unroll
    for (int i = 0; i < 4; ++i) gload_lds16(pa + (size_t)i * 64 * DDIM + ko, la + i * 4096);
#pragma unroll
    for (int j = 0; j < 2; ++j) gload_lds16(pb + (size_t)j * 64 * DDIM + ko, la + 16384 + j * 4096);
  };
  const int sx = (lg ^ ((l15 >> 1) & 3)) << 4;
  int aoff[8], boff[4];
#pragma unroll
  for (int mf = 0; mf < 8; ++mf) aoff[mf] = (wm * 128 + mf * 16 + l15) * 64 + sx;
#pragma unroll
  for (int nf = 0; nf < 4; ++nf) boff[nf] = 16384 + (wn * 64 + nf * 16 + l15) * 64 + sx;
  f32x4 acc[8][4];
#pragma unroll
  for (int mf = 0; mf < 8; ++mf)
#pragma unroll
    for (int nf = 0; nf < 4; ++nf) {
      f32x4 z = {0.f, 0.f, 0.f, 0.f};
      acc[mf][nf] = z;
    }
  auto compute = [&](int buf) {
    const char* bp = smem + buf * 24576;
    bf16x8 af[8], bfr[4];
#pragma unroll
    for (int mf = 0; mf < 8; ++mf) af[mf] = __builtin_bit_cast(bf16x8, *(const int4*)(bp + aoff[mf]));
#pragma unroll
    for (int nf = 0; nf < 4; ++nf) bfr[nf] = __builtin_bit_cast(bf16x8, *(const int4*)(bp + boff[nf]));
    __builtin_amdgcn_s_setprio(1);
#pragma unroll
    for (int mf = 0; mf < 8; ++mf)
#pragma unroll
      for (int nf = 0; nf < 4; ++nf)
        acc[mf][nf] = __builtin_amdgcn_mfma_f32_16x16x32_bf16(af[mf], bfr[nf], acc[mf][nf], 0, 0, 0);
    __builtin_amdgcn_s_setprio(0);
  };
  stage(0, 0);
  stage(1, 1);
  int sb = 2, cb = 0;
  for (int kt = 0; kt < 34; ++kt) {
    stage(sb, kt + 2);
    sb = (sb == 2) ? 0 : sb + 1;
    asm volatile("s_waitcnt vmcnt(12)" ::: "memory");
    __builtin_amdgcn_s_barrier();
    __builtin_amdgcn_sched_barrier(0);
    compute(cb);
    __builtin_amdgcn_s_barrier();
    cb = (cb == 2) ? 0 : cb + 1;
  }
  asm volatile("s_waitcnt vmcnt(6)" ::: "memory");
  __builtin_amdgcn_s_barrier();
  __builtin_amdgcn_sched_barrier(0);
  compute(cb);
  cb = (cb == 2) ? 0 : cb + 1;
  asm volatile("s_waitcnt vmcnt(0)" ::: "memory");
  __builtin_amdgcn_s_barrier();
  __builtin_amdgcn_sched_barrier(0);
  compute(cb);
  float rn[4];
#pragma unroll
  for (int nf = 0; nf < 4; ++nf) rn[nf] = rnorm[sbase + wn * 64 + nf * 16 + l15];
#pragma unroll
  for (int mf = 0; mf < 8; ++mf)
#pragma unroll
    for (int r = 0; r < 4; ++r) {
      float v = -3.0e38f;
      int bi = 0;
#pragma unroll
      for (int nf = 0; nf < 4; ++nf) {
        float x = acc[mf][nf][r] * rn[nf];
        int col = sbase + wn * 64 + nf * 16 + l15;
        if (x > v) { v = x; bi = col; }
      }
#pragma unroll
      for (int m = 1; m < 16; m <<= 1) {
        float ov = __shfl_xor(v, m, 64);
        int oi = __shfl_xor(bi, m, 64);
        if (ov > v || (ov == v && oi < bi)) { v = ov; bi = oi; }
      }
      if (l15 == 0) {
        int row = bm0 + wm * 128 + mf * 16 + lg * 4 + r;
        unsigned u = __float_as_uint(v);
        u ^= (unsigned)((int)u >> 31) | 0x80000000u;
        unsigned long long key = ((unsigned long long)u << 32) | (unsigned)(0xFFFFFFFFu ^ (unsigned)bi);
        atomicMax(keytab + row, key);
      }
    }
}

__global__ __launch_bounds__(256)
void recon_old(const __bf16* __restrict__ Pc, const __bf16* __restrict__ Ps,
               const unsigned long long* __restrict__ keytab, float* __restrict__ out) {
  const int pix = blockIdx.x * 2 + (threadIdx.x >> 7);
  const int c = threadIdx.x & 127;
  const int y = pix / WW, x = pix - (pix / WW) * WW;
  float sum = 0.f, cnt = 0.f;
#pragma unroll
  for (int ki = 0; ki < 3; ++ki) {
    int yn = y - ki + 1;
    if (yn < 0 || yn >= HH) continue;
#pragma unroll
    for (int kj = 0; kj < 3; ++kj) {
      int xn = x - kj + 1;
      if (xn < 0 || xn >= WW) continue;
      cnt += 1.f;
      int m = (int)(0xFFFFFFFFu ^ (unsigned)(keytab[yn * WW + xn] & 0xFFFFFFFFull));
      sum += (float)Ps[(size_t)m * DDIM + c * 9 + ki * 3 + kj];
    }
  }
  float recon = sum / (cnt + 1e-8f);
  float cv = (float)Pc[(size_t)pix * DDIM + c * 9 + 4];
  float diff = cv - recon;
  float sq = diff * diff;
#pragma unroll
  for (int m = 32; m > 0; m >>= 1) sq += __shfl_down(sq, m, 64);
  __shared__ float wsum[4];
  int lane = threadIdx.x & 63, w = threadIdx.x >> 6;
  if (lane == 0) wsum[w] = sq;
  __syncthreads();
  if (threadIdx.x == 0)
    atomicAdd(out, (wsum[0] + wsum[1] + wsum[2] + wsum[3]) * (1.0f / (float)TOTAL_ELEMS));
}

extern "C" void kernel_launch(void* const* d_in, const int* in_sizes, int n_in,
                              void* d_out, int out_size, void* d_ws, size_t ws_size,
                              hipStream_t stream) {
  const float* content = (const float*)d_in[0];
  const float* stylef = (const float*)d_in[1];
  float* out = (float*)d_out;
  char* ws = (char*)d_ws;

  if (ws_size >= NEED_NEW) {
    _Float16* Gg = (_Float16*)ws;
    _Float16* Ct = (_Float16*)(ws + CT_OFF);
    _Float16* St = (_Float16*)(ws + ST2_OFF);
    float* styT = (float*)(ws + STYT_OFF);
    float* ss = (float*)(ws + SS_OFF);
    float* rnorm = (float*)(ws + RN2_OFF);
    unsigned long long* keytab = (unsigned long long*)(ws + KEY2_OFF);

    transpose_kernel<<<dim3(96, 2), 256, 0, stream>>>(stylef, content, St, Ct, styT, ss,
                                                      keytab, out);
    boxnorm_kernel<<<NPIX / 256, 256, 0, stream>>>(ss, rnorm);
    ggemm_kernel<<<dim3(72, 72), 256, 0, stream>>>(Ct, St, (unsigned short*)Gg);
    dist_argmax_kernel<<<DBLK, 256, 0, stream>>>(Gg, rnorm, keytab);
    recon_mse2_kernel<<<NPIX / 2, 256, 0, stream>>>(Ct, styT, keytab, out);
  } else {
    const size_t PS_OFF = 0;
    const size_t PC_OFF = (size_t)NPIX * DDIM * 2;
    const size_t RN_OFF = PC_OFF * 2;
    const size_t KEY_OFF = RN_OFF + (size_t)NPIX * 4;
    __bf16* Ps = (__bf16*)(ws + PS_OFF);
    __bf16* Pc = (__bf16*)(ws + PC_OFF);
    float* rnorm = (float*)(ws + RN_OFF);
    unsigned long long* keytab = (unsigned long long*)(ws + KEY_OFF);
    hipMemsetAsync(d_out, 0, (size_t)out_size * sizeof(float), stream);
    hipMemsetAsync(keytab, 0, (size_t)NPIX * 8, stream);
    build_patches_old<<<dim3(96, 4, 2), 256, 0, stream>>>(stylef, content, Ps, Pc);
    norm_old<<<NPIX / 4, 256, 0, stream>>>(Ps, rnorm);
    gemm_old<<<2592, 256, 0, stream>>>(Pc, Ps, rnorm, keytab);
    recon_old<<<NPIX / 2, 256, 0, stream>>>(Pc, Ps, keytab, out);
  }
}

// Round 14
// 202.545 us; speedup vs baseline: 1.1661x; 1.1661x over previous
//
#include <hip/hip_runtime.h>
#include <hip/hip_bf16.h>

#define HH 96
#define WW 96
#define NPIX 9216
#define NCH 128
#define DDIM 1152
#define TOTAL_ELEMS 1179648
#define CG 32
#define DDIAG 9217
#define DROW 884832

// dist tile params: 8 n x 512 m, 3 bands of 10x528 staged in LDS (31.7KB)
#define NTIL 8
#define MTIL 512
#define BROWS 10
#define BCOLS 528
#define BELEMS (BROWS * BCOLS)          // 5280
#define DCHUNKS 1980                    // 3*BELEMS/8
#define NTB 1152
#define DBLK 20736                      // NTB*18

typedef float f32x4 __attribute__((ext_vector_type(4)));
typedef __bf16 bf16x8 __attribute__((ext_vector_type(8)));
typedef _Float16 half8 __attribute__((ext_vector_type(8)));

__device__ __forceinline__ void gload_lds16(const void* g, void* l) {
  __builtin_amdgcn_global_load_lds((const __attribute__((address_space(1))) void*)g,
                                   (__attribute__((address_space(3))) void*)l, 16, 0, 0);
}

// ======================= NEW PATH (G-factorized, f16) =======================
#define GUARD_ELEMS 894064ull
constexpr size_t G_CORE_ELEMS = (size_t)NPIX * NPIX;
constexpr size_t G_TOT_ELEMS = G_CORE_ELEMS + 2ull * GUARD_ELEMS;
constexpr size_t GBYTES = ((G_TOT_ELEMS * 2 + 255) & ~(size_t)255);
constexpr size_t CT_OFF = GBYTES;
constexpr size_t ST2_OFF = CT_OFF + (size_t)NPIX * NCH * 2;
constexpr size_t STYT_OFF = ST2_OFF + (size_t)NPIX * NCH * 2;
constexpr size_t SS_OFF = STYT_OFF + (size_t)NPIX * NCH * 4;
constexpr size_t RN2_OFF = SS_OFF + (size_t)NPIX * 4;
constexpr size_t KEY2_OFF = RN2_OFF + (size_t)NPIX * 4;
constexpr size_t NEED_NEW = KEY2_OFF + (size_t)NPIX * 8;
constexpr long GUARD_I4 = 111758;        // GUARD_ELEMS*2/16

// features [c][pix] f32 -> [pix][c] f16 (+ styT f32, per-pixel ss); also zeroes keytab/out
__global__ __launch_bounds__(256)
void transpose_kernel(const float* __restrict__ style_f, const float* __restrict__ content_f,
                      _Float16* __restrict__ St, _Float16* __restrict__ Ct,
                      float* __restrict__ styT, float* __restrict__ ss,
                      unsigned long long* __restrict__ keytab, float* __restrict__ out) {
  __shared__ float ftile[NCH][97];
  const int y = blockIdx.x;
  const bool is_style = (blockIdx.y == 0);
  const float* f = is_style ? style_f : content_f;
  _Float16* P = is_style ? St : Ct;
  const int tid = threadIdx.x;
  if (is_style) {
    int g = y * 256 + tid;
    if (g < NPIX) keytab[g] = 0ull;
    if (g == 0) *out = 0.f;
  }
  for (int i = tid; i < NCH * WW; i += 256) {
    int c = i / WW, x = i - (i / WW) * WW;
    ftile[c][x] = f[(size_t)c * NPIX + y * WW + x];
  }
  __syncthreads();
  for (int j = tid; j < WW * NCH; j += 256) {
    int x = j >> 7, c = j & 127;
    float v = ftile[c][x];
    P[(size_t)(y * WW + x) * NCH + c] = (_Float16)v;
    if (is_style) styT[(size_t)(y * WW + x) * NCH + c] = v;
  }
  if (is_style && tid < WW) {
    float s = 0.f;
#pragma unroll 8
    for (int c = 0; c < NCH; ++c) { float v = ftile[c][tid]; s = fmaf(v, v, s); }
    ss[y * WW + tid] = s;
  }
}

__global__ __launch_bounds__(256)
void boxnorm_kernel(const float* __restrict__ ss, float* __restrict__ rnorm) {
  int m = blockIdx.x * 256 + threadIdx.x;
  int ym = m / WW, xm = m - (m / WW) * WW;
  float s = 0.f;
#pragma unroll
  for (int di = -1; di <= 1; ++di) {
    int yy = ym + di;
    if (yy < 0 || yy >= HH) continue;
#pragma unroll
    for (int dj = -1; dj <= 1; ++dj) {
      int xx = xm + dj;
      if (xx < 0 || xx >= WW) continue;
      s += ss[yy * WW + xx];
    }
  }
  rnorm[m] = 1.0f / fmaxf(sqrtf(s), 1e-12f);
}

// G-GEMM (also zeroes the guard bands: 22 int4/side/block, disjoint from core)
__global__ __launch_bounds__(256, 2)
void ggemm_kernel(const _Float16* __restrict__ Ct, const _Float16* __restrict__ St,
                  unsigned short* __restrict__ Gg) {
  __shared__ char smem[65536];
  const int tid = threadIdx.x;
  const int lane = tid & 63, wid = tid >> 6;
  const int l15 = lane & 15, lg = lane >> 4;
  const int wm = wid >> 1, wn = wid & 1;
  const int n0 = blockIdx.x * 128, m0 = blockIdx.y * 128;

  {  // guard zeroing
    const long bidf = (long)blockIdx.y * gridDim.x + blockIdx.x;
    if (tid < 64) {
      int side = tid >> 5, k = tid & 31;
      if (k < 22) {
        long q = bidf * 22 + k;
        if (q < GUARD_I4) {
          int4 z = {0, 0, 0, 0};
          _Float16* gp = (_Float16*)Gg + (side ? (long)(GUARD_ELEMS + G_CORE_ELEMS) : 0l);
          *(int4*)(gp + q * 8) = z;
        }
      }
    }
  }
  {  // stage A,B with slot-XOR swizzle
    const int r = tid >> 4, p = tid & 15;
    const int l = p ^ (r & 7);
    const _Float16* sa = Ct + (size_t)(n0 + r) * NCH + l * 8;
    const _Float16* sb = St + (size_t)(m0 + r) * NCH + l * 8;
    char* d = smem + tid * 16;
#pragma unroll
    for (int i = 0; i < 8; ++i) {
      gload_lds16(sa + (size_t)16 * i * NCH, d + 4096 * i);
      gload_lds16(sb + (size_t)16 * i * NCH, d + 32768 + 4096 * i);
    }
  }
  __syncthreads();

  f32x4 acc[4][4];
#pragma unroll
  for (int mf = 0; mf < 4; ++mf)
#pragma unroll
    for (int nf = 0; nf < 4; ++nf) {
      f32x4 z = {0.f, 0.f, 0.f, 0.f};
      acc[mf][nf] = z;
    }
#pragma unroll
  for (int ks = 0; ks < 4; ++ks) {
    half8 af[4], bb[4];
#pragma unroll
    for (int mf = 0; mf < 4; ++mf) {
      int row = wm * 64 + mf * 16 + l15;
      int phys = (ks * 4 + lg) ^ (row & 7);
      af[mf] = __builtin_bit_cast(half8, *(const int4*)(smem + row * 256 + phys * 16));
    }
#pragma unroll
    for (int nf = 0; nf < 4; ++nf) {
      int row = wn * 64 + nf * 16 + l15;
      int phys = (ks * 4 + lg) ^ (row & 7);
      bb[nf] = __builtin_bit_cast(half8, *(const int4*)(smem + 32768 + row * 256 + phys * 16));
    }
#pragma unroll
    for (int mf = 0; mf < 4; ++mf)
#pragma unroll
      for (int nf = 0; nf < 4; ++nf)
        acc[mf][nf] = __builtin_amdgcn_mfma_f32_16x16x32_f16(af[mf], bb[nf], acc[mf][nf], 0, 0, 0);
  }
  __syncthreads();
#pragma unroll
  for (int mf = 0; mf < 4; ++mf)
#pragma unroll
    for (int nf = 0; nf < 4; ++nf)
#pragma unroll
      for (int r = 0; r < 4; ++r) {
        int row = wm * 64 + mf * 16 + lg * 4 + r;
        int col = wn * 64 + nf * 16 + l15;
        *(_Float16*)(smem + (row * 136 + col) * 2) = (_Float16)acc[mf][nf][r];
      }
  __syncthreads();
  const size_t gbase = GUARD_ELEMS + (size_t)n0 * NPIX + m0;
#pragma unroll
  for (int j = 0; j < 8; ++j) {
    int idx = j * 256 + tid;
    int row = idx >> 4, ch = idx & 15;
    int4 v = *(const int4*)(smem + (row * 136 + ch * 8) * 2);
    *(int4*)(Gg + gbase + (size_t)row * NPIX + ch * 8) = v;
  }
}

// dist + argmax (round-12 v5, best measured: 79 us, VGPR 44, no spill):
// block = 8 n x 512 m, 4 waves (2 n each); 3 band subtiles staged once;
// all taps via aligned b128 LDS reads; keyed atomic merge.
__global__ __launch_bounds__(256, 5)
void dist_argmax_kernel(const _Float16* __restrict__ Gg, const float* __restrict__ rnorm,
                        unsigned long long* __restrict__ keytab) {
  __shared__ _Float16 lds[3 * BELEMS];
  const int bid = blockIdx.x;
  const int idx = (bid & 7) * (DBLK / 8) + (bid >> 3);
  const int mtb = idx / NTB;
  const int ntb = idx - mtb * NTB;
  const int n0 = ntb * NTIL;
  const int m0 = mtb * MTIL;
  const int tid = threadIdx.x;
  const int w = tid >> 6, lane = tid & 63;

  long flat0[3];
#pragma unroll
  for (int b = 0; b < 3; ++b) {
    int di = b - 1;
    flat0[b] = (long)(n0 + 96 * di - 1) * NPIX + (long)(m0 + 96 * di - 8) + (long)GUARD_ELEMS;
  }
#pragma unroll
  for (int k = 0; k < 8; ++k) {
    int q = k * 256 + tid;
    if (q < DCHUNKS) {
      int b = q / 660;
      int rem = q - b * 660;
      int row = rem / 66;
      int c16 = rem - row * 66;
      gload_lds16(Gg + flat0[b] + (long)row * NPIX + c16 * 8, lds + (size_t)q * 8);
    }
  }
  const int mlane = m0 + lane * 8;
  const int ym = mlane / WW;
  const int x8 = mlane - ym * WW;
  const float me0 = (x8 == 0) ? 0.f : 1.f;
  const float me7 = (x8 == 88) ? 0.f : 1.f;
  const bool myr0 = (ym >= 1), myr2 = (ym <= 94);
  float rnv[8];
  *(f32x4*)(rnv) = *(const f32x4*)(rnorm + mlane);
  *(f32x4*)(rnv + 4) = *(const f32x4*)(rnorm + mlane + 4);
  const int col8 = lane * 8 + 8;
  const _Float16* B0p = lds;
  const _Float16* B1p = lds + BELEMS;
  const _Float16* B2p = lds + 2 * BELEMS;

  asm volatile("s_waitcnt vmcnt(0)" ::: "memory");
  __builtin_amdgcn_s_barrier();

#pragma unroll
  for (int s = 0; s < 2; ++s) {
    const int r = w * 2 + s;
    const int n = n0 + r;
    const int yn = n / WW;
    const int xn = n - yn * WW;
    const float cn0 = (xn >= 1) ? 1.f : 0.f;
    const float cn2 = (xn <= 94) ? 1.f : 0.f;
    const float Bw0 = (myr0 && (yn >= 1)) ? 1.f : 0.f;
    const float Bw2 = (myr2 && (yn <= 94)) ? 1.f : 0.f;
    float d[8];
    {  // band di=0 (weight 1)
      const _Float16* bp = B1p + r * BCOLS;
      half8 Vp = *(const half8*)(bp + col8 - 8);
      half8 V0 = *(const half8*)(bp + col8);
      half8 V1 = *(const half8*)(bp + BCOLS + col8);
      half8 V2 = *(const half8*)(bp + 2 * BCOLS + col8);
      half8 Vx = *(const half8*)(bp + 2 * BCOLS + col8 + 8);
      float P = (float)Vp[7];
      float X = (float)Vx[0];
#pragma unroll
      for (int j = 0; j < 8; ++j) d[j] = (float)V1[j];
      d[0] = fmaf(P, cn0 * me0, d[0]);
#pragma unroll
      for (int j = 1; j < 8; ++j) d[j] = fmaf((float)V0[j - 1], cn0, d[j]);
#pragma unroll
      for (int j = 0; j < 7; ++j) d[j] = fmaf((float)V2[j + 1], cn2, d[j]);
      d[7] = fmaf(X, cn2 * me7, d[7]);
    }
    {  // band di=-1 (weight Bw0)
      const float wl = Bw0 * cn0, wr = Bw0 * cn2;
      const _Float16* bp = B0p + r * BCOLS;
      half8 Vp = *(const half8*)(bp + col8 - 8);
      half8 V0 = *(const half8*)(bp + col8);
      half8 V1 = *(const half8*)(bp + BCOLS + col8);
      half8 V2 = *(const half8*)(bp + 2 * BCOLS + col8);
      half8 Vx = *(const half8*)(bp + 2 * BCOLS + col8 + 8);
      float P = (float)Vp[7];
      float X = (float)Vx[0];
#pragma unroll
      for (int j = 0; j < 8; ++j) d[j] = fmaf((float)V1[j], Bw0, d[j]);
      d[0] = fmaf(P, wl * me0, d[0]);
#pragma unroll
      for (int j = 1; j < 8; ++j) d[j] = fmaf((float)V0[j - 1], wl, d[j]);
#pragma unroll
      for (int j = 0; j < 7; ++j) d[j] = fmaf((float)V2[j + 1], wr, d[j]);
      d[7] = fmaf(X, wr * me7, d[7]);
    }
    {  // band di=+1 (weight Bw2)
      const float wl = Bw2 * cn0, wr = Bw2 * cn2;
      const _Float16* bp = B2p + r * BCOLS;
      half8 Vp = *(const half8*)(bp + col8 - 8);
      half8 V0 = *(const half8*)(bp + col8);
      half8 V1 = *(const half8*)(bp + BCOLS + col8);
      half8 V2 = *(const half8*)(bp + 2 * BCOLS + col8);
      half8 Vx = *(const half8*)(bp + 2 * BCOLS + col8 + 8);
      float P = (float)Vp[7];
      float X = (float)Vx[0];
#pragma unroll
      for (int j = 0; j < 8; ++j) d[j] = fmaf((float)V1[j], Bw2, d[j]);
      d[0] = fmaf(P, wl * me0, d[0]);
#pragma unroll
      for (int j = 1; j < 8; ++j) d[j] = fmaf((float)V0[j - 1], wl, d[j]);
#pragma unroll
      for (int j = 0; j < 7; ++j) d[j] = fmaf((float)V2[j + 1], wr, d[j]);
      d[7] = fmaf(X, wr * me7, d[7]);
    }
    // per-lane argmax (ascending m; strict > keeps first max)
    float bv = d[0] * rnv[0];
    int bj = mlane;
#pragma unroll
    for (int j = 1; j < 8; ++j) {
      float xs = d[j] * rnv[j];
      if (xs > bv) { bv = xs; bj = mlane + j; }
    }
    // value-only wave max; tie lanes all publish, key resolves min-index
    float wmx = bv;
#pragma unroll
    for (int mm = 1; mm < 64; mm <<= 1)
      wmx = fmaxf(wmx, __shfl_xor(wmx, mm, 64));
    if (bv == wmx) {
      unsigned u = __float_as_uint(bv);
      u ^= (unsigned)((int)u >> 31) | 0x80000000u;
      unsigned long long key =
          ((unsigned long long)u << 32) | (unsigned)(0xFFFFFFFFu ^ (unsigned)bj);
      atomicMax(keytab + n, key);
    }
  }
}

// recon+MSE
__global__ __launch_bounds__(256)
void recon_mse2_kernel(const _Float16* __restrict__ Ct, const float* __restrict__ styT,
                       const unsigned long long* __restrict__ keytab, float* __restrict__ out) {
  const int pix = blockIdx.x * 2 + (threadIdx.x >> 7);
  const int c = threadIdx.x & 127;
  const int y = pix / WW, x = pix - (pix / WW) * WW;
  float sum = 0.f, cnt = 0.f;
#pragma unroll
  for (int ki = 0; ki < 3; ++ki) {
    int yn = y - ki + 1;
    if (yn < 0 || yn >= HH) continue;
#pragma unroll
    for (int kj = 0; kj < 3; ++kj) {
      int xn = x - kj + 1;
      if (xn < 0 || xn >= WW) continue;
      cnt += 1.f;
      int m = (int)(0xFFFFFFFFu ^ (unsigned)(keytab[yn * WW + xn] & 0xFFFFFFFFull));
      int ys = m / WW, xs = m - (m / WW) * WW;
      int sy = ys + ki - 1, sx = xs + kj - 1;
      if (sy >= 0 && sy < HH && sx >= 0 && sx < WW)
        sum += styT[(size_t)(sy * WW + sx) * NCH + c];
    }
  }
  float recon = sum / (cnt + 1e-8f);
  float cv = (float)Ct[(size_t)pix * NCH + c];
  float diff = cv - recon;
  float sq = diff * diff;
#pragma unroll
  for (int m = 32; m > 0; m >>= 1) sq += __shfl_down(sq, m, 64);
  __shared__ float wsum[4];
  int lane = threadIdx.x & 63, w = threadIdx.x >> 6;
  if (lane == 0) wsum[w] = sq;
  __syncthreads();
  if (threadIdx.x == 0)
    atomicAdd(out, (wsum[0] + wsum[1] + wsum[2] + wsum[3]) * (1.0f / (float)TOTAL_ELEMS));
}

// ======================= OLD PATH (round-3, fallback) =======================
__global__ __launch_bounds__(256)
void build_patches_old(const float* __restrict__ style_f, const float* __restrict__ content_f,
                       __bf16* __restrict__ Ps, __bf16* __restrict__ Pc) {
  __shared__ float ftile[CG][3][104];
  const int y = blockIdx.x;
  const int cg = blockIdx.y;
  const bool is_style = (blockIdx.z == 0);
  const float* f = is_style ? style_f : content_f;
  __bf16* P = is_style ? Ps : Pc;
  const int tid = threadIdx.x;
  for (int i = tid; i < CG * 3 * 96; i += 256) {
    int cl = i / 288, rem = i - cl * 288;
    int yy = rem / 96, xx = rem - yy * 96;
    int gy = y + yy - 1;
    float v = (gy >= 0 && gy < HH) ? f[(size_t)(cg * CG + cl) * NPIX + gy * WW + xx] : 0.f;
    ftile[cl][yy][xx] = v;
  }
  __syncthreads();
  for (int j = tid; j < 96 * 36; j += 256) {
    int px = j / 36, wi = j - px * 36;
    bf16x8 tmp;
#pragma unroll
    for (int u = 0; u < 8; ++u) {
      int e = wi * 8 + u;
      int cl = e / 9, t = e - cl * 9;
      int ki = t / 3, kj = t - ki * 3;
      int xx = px + kj - 1;
      float v = (xx >= 0 && xx < WW) ? ftile[cl][ki][xx] : 0.f;
      tmp[u] = (__bf16)v;
    }
    *(bf16x8*)(P + (size_t)(y * WW + px) * DDIM + cg * 288 + wi * 8) = tmp;
  }
}

__global__ __launch_bounds__(256)
void norm_old(const __bf16* __restrict__ Ps, float* __restrict__ rnorm) {
  const int n = blockIdx.x * 4 + (threadIdx.x >> 6);
  const int lane = threadIdx.x & 63;
  const bf16x8* row = (const bf16x8*)(Ps + (size_t)n * DDIM);
  float ss = 0.f;
#pragma unroll
  for (int i = 0; i < 3; ++i) {
    int idx = i * 64 + lane;
    if (idx < 144) {
      bf16x8 v = row[idx];
#pragma unroll
      for (int u = 0; u < 8; ++u) { float x = (float)v[u]; ss += x * x; }
    }
  }
#pragma unroll
  for (int m = 1; m < 64; m <<= 1) ss += __shfl_xor(ss, m, 64);
  if (lane == 0) rnorm[n] = 1.0f / fmaxf(sqrtf(ss), 1e-12f);
}

__global__ __launch_bounds__(256, 2)
void gemm_old(const __bf16* __restrict__ Pc, const __bf16* __restrict__ Ps,
              const float* __restrict__ rnorm, unsigned long long* __restrict__ keytab) {
  __shared__ int4 smem4[4608];
  char* smem = (char*)smem4;
  const int tid = threadIdx.x;
  const int lane = tid & 63;
  const int wid = tid >> 6;
  const int l15 = lane & 15;
  const int lg = lane >> 4;
  const int wm = wid >> 1;
  const int wn = wid & 1;
  const int orig = blockIdx.x;
  const int swz = (orig & 7) * 324 + (orig >> 3);
  const int mt = swz / 72;
  const int nt = swz - mt * 72;
  const int bm0 = mt * 256;
  const int sbase = nt * 128;
  const int srow = tid >> 2;
  const int sg = (tid & 3) ^ ((srow >> 1) & 3);
  const __bf16* pa = Pc + (size_t)(bm0 + srow) * DDIM + sg * 8;
  const __bf16* pb = Ps + (size_t)(sbase + srow) * DDIM + sg * 8;
  const int sdst = tid * 16;
  auto stage = [&](int buf, int kt) {
    char* la = smem + buf * 24576 + sdst;
    const int ko = kt * 32;
#pragma unroll
    for (int i = 0; i < 4; ++i) gload_lds16(pa + (size_t)i * 64 * DDIM + ko, la + i * 4096);
#pragma unroll
    for (int j = 0; j < 2; ++j) gload_lds16(pb + (size_t)j * 64 * DDIM + ko, la + 16384 + j * 4096);
  };
  const int sx = (lg ^ ((l15 >> 1) & 3)) << 4;
  int aoff[8], boff[4];
#pragma unroll
  for (int mf = 0; mf < 8; ++mf) aoff[mf] = (wm * 128 + mf * 16 + l15) * 64 + sx;
#pragma unroll
  for (int nf = 0; nf < 4; ++nf) boff[nf] = 16384 + (wn * 64 + nf * 16 + l15) * 64 + sx;
  f32x4 acc[8][4];
#pragma unroll
  for (int mf = 0; mf < 8; ++mf)
#pragma unroll
    for (int nf = 0; nf < 4; ++nf) {
      f32x4 z = {0.f, 0.f, 0.f, 0.f};
      acc[mf][nf] = z;
    }
  auto compute = [&](int buf) {
    const char* bp = smem + buf * 24576;
    bf16x8 af[8], bfr[4];
#pragma unroll
    for (int mf = 0; mf < 8; ++mf) af[mf] = __builtin_bit_cast(bf16x8, *(const int4*)(bp + aoff[mf]));
#pragma unroll
    for (int nf = 0; nf < 4; ++nf) bfr[nf] = __builtin_bit_cast(bf16x8, *(const int4*)(bp + boff[nf]));
    __builtin_amdgcn_s_setprio(1);
#pragma unroll
    for (int mf = 0; mf < 8; ++mf)
#pragma unroll
      for (int nf = 0; nf < 4; ++nf)
        acc[mf][nf] = __builtin_amdgcn_mfma_f32_16x16x32_bf16(af[mf], bfr[nf], acc[mf][nf], 0, 0, 0);
    __builtin_amdgcn_s_setprio(0);
  };
  stage(0, 0);
  stage(1, 1);
  int sb = 2, cb = 0;
  for (int kt = 0; kt < 34; ++kt) {
    stage(sb, kt + 2);
    sb = (sb == 2) ? 0 : sb + 1;
    asm volatile("s_waitcnt vmcnt(12)" ::: "memory");
    __builtin_amdgcn_s_barrier();
    __builtin_amdgcn_sched_barrier(0);
    compute(cb);
    __builtin_amdgcn_s_barrier();
    cb = (cb == 2) ? 0 : cb + 1;
  }
  asm volatile("s_waitcnt vmcnt(6)" ::: "memory");
  __builtin_amdgcn_s_barrier();
  __builtin_amdgcn_sched_barrier(0);
  compute(cb);
  cb = (cb == 2) ? 0 : cb + 1;
  asm volatile("s_waitcnt vmcnt(0)" ::: "memory");
  __builtin_amdgcn_s_barrier();
  __builtin_amdgcn_sched_barrier(0);
  compute(cb);
  float rn[4];
#pragma unroll
  for (int nf = 0; nf < 4; ++nf) rn[nf] = rnorm[sbase + wn * 64 + nf * 16 + l15];
#pragma unroll
  for (int mf = 0; mf < 8; ++mf)
#pragma unroll
    for (int r = 0; r < 4; ++r) {
      float v = -3.0e38f;
      int bi = 0;
#pragma unroll
      for (int nf = 0; nf < 4; ++nf) {
        float x = acc[mf][nf][r] * rn[nf];
        int col = sbase + wn * 64 + nf * 16 + l15;
        if (x > v) { v = x; bi = col; }
      }
#pragma unroll
      for (int m = 1; m < 16; m <<= 1) {
        float ov = __shfl_xor(v, m, 64);
        int oi = __shfl_xor(bi, m, 64);
        if (ov > v || (ov == v && oi < bi)) { v = ov; bi = oi; }
      }
      if (l15 == 0) {
        int row = bm0 + wm * 128 + mf * 16 + lg * 4 + r;
        unsigned u = __float_as_uint(v);
        u ^= (unsigned)((int)u >> 31) | 0x80000000u;
        unsigned long long key = ((unsigned long long)u << 32) | (unsigned)(0xFFFFFFFFu ^ (unsigned)bi);
        atomicMax(keytab + row, key);
      }
    }
}

__global__ __launch_bounds__(256)
void recon_old(const __bf16* __restrict__ Pc, const __bf16* __restrict__ Ps,
               const unsigned long long* __restrict__ keytab, float* __restrict__ out) {
  const int pix = blockIdx.x * 2 + (threadIdx.x >> 7);
  const int c = threadIdx.x & 127;
  const int y = pix / WW, x = pix - (pix / WW) * WW;
  float sum = 0.f, cnt = 0.f;
#pragma unroll
  for (int ki = 0; ki < 3; ++ki) {
    int yn = y - ki + 1;
    if (yn < 0 || yn >= HH) continue;
#pragma unroll
    for (int kj = 0; kj < 3; ++kj) {
      int xn = x - kj + 1;
      if (xn < 0 || xn >= WW) continue;
      cnt += 1.f;
      int m = (int)(0xFFFFFFFFu ^ (unsigned)(keytab[yn * WW + xn] & 0xFFFFFFFFull));
      sum += (float)Ps[(size_t)m * DDIM + c * 9 + ki * 3 + kj];
    }
  }
  float recon = sum / (cnt + 1e-8f);
  float cv = (float)Pc[(size_t)pix * DDIM + c * 9 + 4];
  float diff = cv - recon;
  float sq = diff * diff;
#pragma unroll
  for (int m = 32; m > 0; m >>= 1) sq += __shfl_down(sq, m, 64);
  __shared__ float wsum[4];
  int lane = threadIdx.x & 63, w = threadIdx.x >> 6;
  if (lane == 0) wsum[w] = sq;
  __syncthreads();
  if (threadIdx.x == 0)
    atomicAdd(out, (wsum[0] + wsum[1] + wsum[2] + wsum[3]) * (1.0f / (float)TOTAL_ELEMS));
}

extern "C" void kernel_launch(void* const* d_in, const int* in_sizes, int n_in,
                              void* d_out, int out_size, void* d_ws, size_t ws_size,
                              hipStream_t stream) {
  const float* content = (const float*)d_in[0];
  const float* stylef = (const float*)d_in[1];
  float* out = (float*)d_out;
  char* ws = (char*)d_ws;

  if (ws_size >= NEED_NEW) {
    _Float16* Gg = (_Float16*)ws;
    _Float16* Ct = (_Float16*)(ws + CT_OFF);
    _Float16* St = (_Float16*)(ws + ST2_OFF);
    float* styT = (float*)(ws + STYT_OFF);
    float* ss = (float*)(ws + SS_OFF);
    float* rnorm = (float*)(ws + RN2_OFF);
    unsigned long long* keytab = (unsigned long long*)(ws + KEY2_OFF);

    transpose_kernel<<<dim3(96, 2), 256, 0, stream>>>(stylef, content, St, Ct, styT, ss,
                                                      keytab, out);
    boxnorm_kernel<<<NPIX / 256, 256, 0, stream>>>(ss, rnorm);
    ggemm_kernel<<<dim3(72, 72), 256, 0, stream>>>(Ct, St, (unsigned short*)Gg);
    dist_argmax_kernel<<<DBLK, 256, 0, stream>>>(Gg, rnorm, keytab);
    recon_mse2_kernel<<<NPIX / 2, 256, 0, stream>>>(Ct, styT, keytab, out);
  } else {
    const size_t PS_OFF = 0;
    const size_t PC_OFF = (size_t)NPIX * DDIM * 2;
    const size_t RN_OFF = PC_OFF * 2;
    const size_t KEY_OFF = RN_OFF + (size_t)NPIX * 4;
    __bf16* Ps = (__bf16*)(ws + PS_OFF);
    __bf16* Pc = (__bf16*)(ws + PC_OFF);
    float* rnorm = (float*)(ws + RN_OFF);
    unsigned long long* keytab = (unsigned long long*)(ws + KEY_OFF);
    hipMemsetAsync(d_out, 0, (size_t)out_size * sizeof(float), stream);
    hipMemsetAsync(keytab, 0, (size_t)NPIX * 8, stream);
    build_patches_old<<<dim3(96, 4, 2), 256, 0, stream>>>(stylef, content, Ps, Pc);
    norm_old<<<NPIX / 4, 256, 0, stream>>>(Ps, rnorm);
    gemm_old<<<2592, 256, 0, stream>>>(Pc, Ps, rnorm, keytab);
    recon_old<<<NPIX / 2, 256, 0, stream>>>(Pc, Ps, keytab, out);
  }
}